// Round 2
// baseline (86.624 us; speedup 1.0000x reference)
//
#include <hip/hip_runtime.h>

// Problem constants from the reference file (fixed by setup_inputs()).
constexpr int Hf = 50, Wf = 50, Cf = 256;
constexpr int PH = 7, PW = 7;
constexpr int C4 = Cf / 4;     // float4 groups per pixel = 64 = one wave
constexpr int Hc = Hf - 3;     // 47 valid 4-row column-max offsets
constexpr int NXCD = 8;        // MI355X XCD count [measured: learn_hip m09]

// ---------------------------------------------------------------------------
// Kernel A: colmax[b][y][x][c] = max_{dy in 0..3} feat[b][y+dy][x][c],
// for all y in [0, Hf-4]. One wave per (b,y,x); lane = c4 group (1 KB
// coalesced per load). All ROIs in this problem are 28x28, so every pool
// bin is an aligned 4x4 max => bin = horizontal 4-max over one colmax row.
// This cuts total cache-request volume 205 MB -> 77 MB (A, L2-local) +
// 51 MB (C) instead of 16 feat loads per bin.
// Blocks are image-major (2350 waves per image); bijective XCD swizzle
// (guide m204) pins each image's ~587 blocks to one XCD so the 4x row
// redundancy is served by that XCD's L2 (2.56 MB image < 4 MB L2).
// ---------------------------------------------------------------------------
__global__ __launch_bounds__(256) void colmax_kernel(
    const float4* __restrict__ feat,   // [B, Hf, Wf, C4]
    float4*       __restrict__ colmax, // [B, Hc, Wf, C4] (workspace)
    int n_waves, int q, int rr) {
  int i   = blockIdx.x;
  int xcd = i % NXCD;
  int w   = (xcd < rr ? xcd * (q + 1) : rr * (q + 1) + (xcd - rr) * q)
          + i / NXCD;

  int wave = w * 4 + (threadIdx.x >> 6);
  if (wave >= n_waves) return;
  int lane = threadIdx.x & 63;

  int b  = wave / (Hc * Wf);
  int r  = wave - b * (Hc * Wf);
  int y  = r / Wf;
  int x  = r - y * Wf;

  const float4* p = feat + ((size_t)(b * Hf + y) * Wf + x) * C4 + lane;
  float4 m = p[0];
#pragma unroll
  for (int dy = 1; dy < 4; ++dy) {
    float4 v = p[(size_t)dy * (Wf * C4)];
    m.x = fmaxf(m.x, v.x);
    m.y = fmaxf(m.y, v.y);
    m.z = fmaxf(m.z, v.z);
    m.w = fmaxf(m.w, v.w);
  }
  colmax[((size_t)(b * Hc + y) * Wf + x) * C4 + lane] = m;
}

// ---------------------------------------------------------------------------
// Kernel C: one wave per output bin; lane = c4 group. Fast path (28x28 ROI,
// always taken for this dataset): bin = max over 4 consecutive colmax
// columns in row y1+4*py. General fallback reads feat directly (correct for
// arbitrary ROIs; never taken here).
// ---------------------------------------------------------------------------
__global__ __launch_bounds__(256) void binmax_kernel(
    const float4* __restrict__ feat,    // [B, Hf, Wf, C4]
    const float4* __restrict__ colmax,  // [B, Hc, Wf, C4]
    const int*    __restrict__ rois,    // [N, 5] (img, x1, y1, x2, y2) incl.
    float4*       __restrict__ out,     // [N, PH, PW, C4]
    int n_bins) {
  int bin = blockIdx.x * 4 + (threadIdx.x >> 6);
  if (bin >= n_bins) return;
  int lane = threadIdx.x & 63;

  int n  = bin / (PH * PW);
  int rb = bin - n * (PH * PW);
  int py = rb / PW;
  int px = rb - py * PW;

  const int* roi = rois + n * 5;
  int img = roi[0];
  int x1  = roi[1];
  int y1  = roi[2];
  int x2  = roi[3];
  int y2  = roi[4];
  int roi_h = y2 - y1 + 1;
  int roi_w = x2 - x1 + 1;

  float4 m;
  if (roi_h == 28 && roi_w == 28) {
    // bin rows = [y1+4py, y1+4py+4), cols = [x1+4px, x1+4px+4)
    const float4* p = colmax
        + ((size_t)(img * Hc + (y1 + 4 * py)) * Wf + (x1 + 4 * px)) * C4 + lane;
    m = p[0];
#pragma unroll
    for (int dx = 1; dx < 4; ++dx) {
      float4 v = p[(size_t)dx * C4];
      m.x = fmaxf(m.x, v.x);
      m.y = fmaxf(m.y, v.y);
      m.z = fmaxf(m.z, v.z);
      m.w = fmaxf(m.w, v.w);
    }
  } else {
    // General adaptive-bin path (reference semantics), direct from feat.
    int hs = (py * roi_h + PH - 1) / PH;
    int he = ((py + 1) * roi_h + PH - 1) / PH;
    int ws = (px * roi_w + PW - 1) / PW;
    int we = ((px + 1) * roi_w + PW - 1) / PW;
    const float4* fb = feat + (size_t)img * (Hf * Wf * C4) + lane;
    m = make_float4(-INFINITY, -INFINITY, -INFINITY, -INFINITY);
    for (int dy = hs; dy < he; ++dy) {
      const float4* prow = fb + (size_t)(y1 + dy) * (Wf * C4);
      for (int dx = ws; dx < we; ++dx) {
        float4 v = prow[(size_t)(x1 + dx) * C4];
        m.x = fmaxf(m.x, v.x);
        m.y = fmaxf(m.y, v.y);
        m.z = fmaxf(m.z, v.z);
        m.w = fmaxf(m.w, v.w);
      }
    }
  }

  out[(size_t)bin * C4 + lane] = m;
}

extern "C" void kernel_launch(void* const* d_in, const int* in_sizes, int n_in,
                              void* d_out, int out_size, void* d_ws, size_t ws_size,
                              hipStream_t stream) {
  const float* feat = (const float*)d_in[0];
  const int*   rois = (const int*)d_in[1];
  // d_in[2]/d_in[3] are pool_height/pool_width = 7/7 (fixed by the reference
  // setup; grid geometry depends on them so they are compile-time here).
  int n_rois   = in_sizes[1] / 5;
  int n_images = in_sizes[0] / (Hf * Wf * Cf);
  int n_bins   = n_rois * PH * PW;

  // Workspace: colmax table, fully rewritten every launch (ws is poisoned).
  float4* colmax = (float4*)d_ws;   // n_images*Hc*Wf*C4 float4 = 19.25 MB

  int waves_a  = n_images * Hc * Wf;
  int blocks_a = (waves_a + 3) / 4;
  int qa  = blocks_a / NXCD;
  int ra  = blocks_a % NXCD;
  colmax_kernel<<<blocks_a, 256, 0, stream>>>(
      (const float4*)feat, colmax, waves_a, qa, ra);

  int blocks_c = (n_bins + 3) / 4;
  binmax_kernel<<<blocks_c, 256, 0, stream>>>(
      (const float4*)feat, colmax, rois, (float4*)d_out, n_bins);
}

// Round 3
// 83.802 us; speedup vs baseline: 1.0337x; 1.0337x over previous
//
#include <hip/hip_runtime.h>

// Problem constants from the reference file (fixed by setup_inputs()).
constexpr int Hf = 50, Wf = 50, Cf = 256;
constexpr int PH = 7, PW = 7, NB = PH * PW;  // 49 bins per ROI
constexpr int C4 = Cf / 4;   // float4 groups per pixel = 64 = one wave
constexpr int NXCD = 8;      // MI355X XCD count [measured: learn_hip m09]

typedef float f32x4 __attribute__((ext_vector_type(4)));

// ---------------------------------------------------------------------------
// Kernel 1: counting-sort ROIs by image into packed meta (2 x int4 per slot:
// {img,x1,y1,n},{x2,y2,-,-}) + per-image {count, base} header. Rebuilt every
// launch (ws is re-poisoned). One broadcast int4 load in the pool kernel
// replaces the order[]->rois[] dependent chain.
// ---------------------------------------------------------------------------
__global__ __launch_bounds__(256) void sort_rois_kernel(
    const int* __restrict__ rois, int n_rois, int n_images,
    int* __restrict__ hdr,        // [2*n_images]: cnt[0..B), base[B..2B)
    int4* __restrict__ meta) {    // [2*n_rois]
  __shared__ int cnt[64], base[64];
  for (int i = threadIdx.x; i < n_images; i += blockDim.x) cnt[i] = 0;
  __syncthreads();
  for (int t = threadIdx.x; t < n_rois; t += blockDim.x)
    atomicAdd(&cnt[rois[t * 5]], 1);
  __syncthreads();
  if (threadIdx.x == 0) {
    int acc = 0;
    for (int i = 0; i < n_images; ++i) {
      base[i] = acc;
      hdr[i] = cnt[i];
      hdr[n_images + i] = acc;
      acc += cnt[i];
    }
  }
  __syncthreads();
  for (int t = threadIdx.x; t < n_rois; t += blockDim.x) {
    const int* r = rois + t * 5;
    int slot = atomicAdd(&base[r[0]], 1);
    meta[2 * slot]     = make_int4(r[0], r[1], r[2], t);
    meta[2 * slot + 1] = make_int4(r[3], r[4], 0, 0);
  }
}

// ---------------------------------------------------------------------------
// Kernel 2: one wave per bin, lane = c4 group. STRICT image<->XCD pinning:
// block i -> XCD i%8 (round-robin dispatch) -> image i%8 only, grid-striding
// that image's bins. Per-XCD L2 read set = one 2.56 MB image < 4 MB L2, so
// the ~10x cross-ROI reuse (185 of 205 MB requests) is L2-resident.
// Output stores are NON-TEMPORAL so the 12.8 MB out-write doesn't
// write-allocate in L2 and evict the image (R1/R2 thrash post-mortem).
// ---------------------------------------------------------------------------
__global__ __launch_bounds__(256) void pool_kernel(
    const float4* __restrict__ feat,   // [B, Hf, Wf, C4]
    const int*    __restrict__ hdr,
    const int4*   __restrict__ meta,
    float4*       __restrict__ out,    // [N, NB, C4]
    int n_images, int bpi) {
  int j = blockIdx.x % n_images;       // image == XCD (when n_images==8)
  int t = blockIdx.x / n_images;
  int cnt    = hdr[j];
  int sbase  = hdr[n_images + j];
  int nb_img = cnt * NB;
  int lane = threadIdx.x & 63;
  int wv   = threadIdx.x >> 6;

  for (int lb = t * 4 + wv; lb < nb_img; lb += bpi * 4) {
    int q  = lb / NB;                  // local roi slot within image
    int rb = lb - q * NB;              // bin within roi
    int s  = sbase + q;                // global sorted slot

    int4 m0 = meta[2 * s];             // {img, x1, y1, n} (wave-uniform bcast)
    int4 m1 = meta[2 * s + 1];         // {x2, y2, -, -}
    int img = m0.x, x1 = m0.y, y1 = m0.z, n = m0.w;
    int roi_h = m1.y - y1 + 1;
    int roi_w = m1.x - x1 + 1;

    int py = rb / PW;
    int px = rb - py * PW;

    const float4* fb = feat + (size_t)img * (Hf * Wf * C4) + lane;
    float4 m = make_float4(-INFINITY, -INFINITY, -INFINITY, -INFINITY);

    if (roi_h == 28 && roi_w == 28) {
      // Dataset case: every bin is an aligned 4x4 max. 16 independent
      // global_load_dwordx4 in flight before the max tree.
      const float4* p0 = fb + (size_t)(y1 + 4 * py) * (Wf * C4)
                            + (size_t)(x1 + 4 * px) * C4;
#pragma unroll
      for (int dy = 0; dy < 4; ++dy) {
        const float4* prow = p0 + (size_t)dy * (Wf * C4);
#pragma unroll
        for (int dx = 0; dx < 4; ++dx) {
          float4 v = prow[(size_t)dx * C4];
          m.x = fmaxf(m.x, v.x);
          m.y = fmaxf(m.y, v.y);
          m.z = fmaxf(m.z, v.z);
          m.w = fmaxf(m.w, v.w);
        }
      }
    } else {
      // General adaptive-bin path (reference semantics; not taken here).
      int hs = (py * roi_h + PH - 1) / PH;
      int he = ((py + 1) * roi_h + PH - 1) / PH;
      int ws = (px * roi_w + PW - 1) / PW;
      int we = ((px + 1) * roi_w + PW - 1) / PW;
      for (int dy = hs; dy < he; ++dy) {
        const float4* prow = fb + (size_t)(y1 + dy) * (Wf * C4);
        for (int dx = ws; dx < we; ++dx) {
          float4 v = prow[(size_t)(x1 + dx) * C4];
          m.x = fmaxf(m.x, v.x);
          m.y = fmaxf(m.y, v.y);
          m.z = fmaxf(m.z, v.z);
          m.w = fmaxf(m.w, v.w);
        }
      }
    }

    // Non-temporal: don't let the streaming out-write evict the image in L2.
    f32x4 val = {m.x, m.y, m.z, m.w};
    __builtin_nontemporal_store(
        val, (f32x4*)(out + ((size_t)n * NB + rb) * C4 + lane));
  }
}

extern "C" void kernel_launch(void* const* d_in, const int* in_sizes, int n_in,
                              void* d_out, int out_size, void* d_ws, size_t ws_size,
                              hipStream_t stream) {
  const float* feat = (const float*)d_in[0];
  const int*   rois = (const int*)d_in[1];
  // d_in[2]/d_in[3] are pool_height/pool_width = 7/7 (fixed by the reference
  // setup; grid geometry depends on them so they are compile-time here).
  int n_rois   = in_sizes[1] / 5;
  int n_images = in_sizes[0] / (Hf * Wf * Cf);
  if (n_images < 1) n_images = 1;

  // ws layout: hdr (2*n_images ints, 16B-aligned block of 64B+) then meta.
  int*  hdr  = (int*)d_ws;
  int4* meta = (int4*)((char*)d_ws + 256);   // 256B offset keeps int4 aligned

  sort_rois_kernel<<<1, 256, 0, stream>>>(rois, n_rois, n_images, hdr, meta);

  // Grid: n_images * bpi blocks; bpi sized for 2x the average ROIs/image,
  // grid-stride covers any skew (correct for arbitrary distributions).
  int avg  = (n_rois + n_images - 1) / n_images;
  int bpi  = (2 * avg * NB + 3) / 4;
  int blocks = n_images * bpi;
  pool_kernel<<<blocks, 256, 0, stream>>>(
      (const float4*)feat, hdr, meta, (float4*)d_out, n_images, bpi);
}